// Round 7
// baseline (49.682 us; speedup 1.0000x reference)
//
#include <hip/hip_runtime.h>

// Fully-fused 4-level db4 wavedec ('symmetric'), faithful to the JAX/pywt reference.
// x: [B=64, L=4096, C=32] f32. Out flat: cA4,cD4,cD3,cD2,cD1 each [B,C,len].
// lens: 4096 -> 2051 -> 1029 -> 518 -> 262.
// Block = (batch, tile of 33 cA4 outputs), ALL 32 channels; 512 blocks x 512 thr.
// Lane 0-31 = channel => every x cache line is read once, fully used (no LDS
// staging of x; level 1 = register sliding window from global). Levels 2-4 go
// through LDS [ch][sample] rows (float2 windows). All cD/cA4 stores direct
// (per-thread consecutive runs; L2 merges). 71.75 KB LDS -> 2 blocks/CU, 512
// blocks = exactly 2 per CU, no tail. 3 barriers total.

#define NT 512

// LDS row pitches (floats), == 2 mod 4: float2 bank-pair maps uniform
// (pitch/2 odd, gcd(pitch/2,16)=1): 161,83,43 all odd & coprime to 16.
#define LP1 322  // span <= 306 (+6 left, +7 right margins = 319)
#define LP2 166  // span <= 150 (+13 = 163)
#define LP3 86   // span <= 72  (+13 = 85)

#define L0C 4096
#define L1C 2051
#define L2C 1029
#define L3C 518
#define L4C 262
#define SC 2048

#define OFF_CD4 ((size_t)SC * L4C)
#define OFF_CD3 ((size_t)2 * SC * L4C)
#define OFF_CD2 (OFF_CD3 + (size_t)SC * L3C)
#define OFF_CD1 (OFF_CD2 + (size_t)SC * L2C)

__device__ __forceinline__ int sym_idx(int t, int L) {
    if (t < 0) t = -1 - t;
    if (t >= L) t = 2 * L - 1 - t;
    return t;
}

__device__ __forceinline__ void filt8(
    const float w0, const float w1, const float w2, const float w3,
    const float w4, const float w5, const float w6, const float w7,
    float& a, float& d) {
    // db4 correlation kernels (dec_lo reversed = _H; dec_hi reversed), split trees.
    constexpr float FLO[8] = {
        0.23037781330885523f,  0.7148465705525415f,  0.6308807679295904f,
        -0.02798376941698385f, -0.18703481171888114f, 0.030841381835986965f,
        0.032883011666982945f, -0.010597401784997278f};
    constexpr float FHI[8] = {
        -0.010597401784997278f, -0.032883011666982945f, 0.030841381835986965f,
        0.18703481171888114f,  -0.02798376941698385f,  -0.6308807679295904f,
        0.7148465705525415f,   -0.23037781330885523f};
    float a0 = FLO[0] * w0;
    a0 = fmaf(FLO[1], w1, a0); a0 = fmaf(FLO[2], w2, a0); a0 = fmaf(FLO[3], w3, a0);
    float a1 = FLO[4] * w4;
    a1 = fmaf(FLO[5], w5, a1); a1 = fmaf(FLO[6], w6, a1); a1 = fmaf(FLO[7], w7, a1);
    a = a0 + a1;
    float d0 = FHI[0] * w0;
    d0 = fmaf(FHI[1], w1, d0); d0 = fmaf(FHI[2], w2, d0); d0 = fmaf(FHI[3], w3, d0);
    float d1 = FHI[4] * w4;
    d1 = fmaf(FHI[5], w5, d1); d1 = fmaf(FHI[6], w6, d1); d1 = fmaf(FHI[7], w7, d1);
    d = d0 + d1;
}

// Level 1: register sliding window straight from global x (channel-coalesced).
template <bool MG>
__device__ __forceinline__ void level1(
    const float* __restrict__ xc,   // x + b*L0C*32 + c (stride 32 per sample)
    float* __restrict__ b1row,      // b1 + c*LP1; word 6 = sample lo1
    float* __restrict__ gcd1,       // out + OFF_CD1 + sig*L1C
    int lo1, int hi1, int slot) {
    constexpr int R = 20;
    const int span = hi1 - lo1;
    const int i0 = lo1 + min(slot * R, (span - R) & ~1);
    float w[8];
#pragma unroll
    for (int k = 0; k < 8; ++k) {
        int t = 2 * i0 - 6 + k;
        if (MG) t = sym_idx(t, L0C);
        w[k] = xc[(size_t)t * 32];
    }
    float aprev = 0.f;
#pragma unroll
    for (int r = 0; r < R; ++r) {
        const int i = i0 + r;
        if (r) {
#pragma unroll
            for (int k = 0; k < 6; ++k) w[k] = w[k + 2];
            int t0 = 2 * i, t1 = 2 * i + 1;
            if (MG) { t0 = sym_idx(t0, L0C); t1 = sym_idx(t1, L0C); }
            w[6] = xc[(size_t)t0 * 32];
            w[7] = xc[(size_t)t1 * 32];
        }
        float a, d;
        filt8(w[0], w[1], w[2], w[3], w[4], w[5], w[6], w[7], a, d);
        gcd1[i] = d;
        if (r & 1)
            *reinterpret_cast<float2*>(b1row + (i - 1 - lo1 + 6)) = make_float2(aprev, a);
        else
            aprev = a;
        if (MG) {
            if (lo1 == 0 && i < 6) b1row[5 - i] = a;
            if (hi1 == L1C && i >= L1C - 7) b1row[(2 * L1C - 1 - i) - lo1 + 6] = a;
        }
    }
    // odd-span tail (tile 7): one uncovered output, scalar window
    if (MG && (span & 1) && slot == 15) {
        const int i = hi1 - 1;
        float ww[8];
#pragma unroll
        for (int k = 0; k < 8; ++k) ww[k] = xc[(size_t)sym_idx(2 * i - 6 + k, L0C) * 32];
        float a, d;
        filt8(ww[0], ww[1], ww[2], ww[3], ww[4], ww[5], ww[6], ww[7], a, d);
        gcd1[i] = d;
        b1row[i - lo1 + 6] = a;
        if (hi1 == L1C && i >= L1C - 7) b1row[(2 * L1C - 1 - i) - lo1 + 6] = a;
    }
}

// Levels 2-3: float2 sliding window over source LDS row, writes next row + cd.
template <int R, bool MG>
__device__ __forceinline__ void levelmid(
    const float* __restrict__ srow, int slo,   // source row, word 6 = sample slo (even)
    float* __restrict__ drow, int DL,          // dest row; this level's full length
    float* __restrict__ gcd,
    int lo, int hi, int slot) {
    const int span = hi - lo;
    const int i0 = lo + min(slot * R, (span - R) & ~1);
    const float2* s2 = reinterpret_cast<const float2*>(srow);
    const int p = i0 - (slo >> 1);  // float2 idx of taps [2i0-6, 2i0-5]
    float2 f0 = s2[p], f1 = s2[p + 1], f2 = s2[p + 2];
    float aprev = 0.f;
#pragma unroll
    for (int r = 0; r < R; ++r) {
        const float2 f3 = s2[p + 3 + r];
        const int i = i0 + r;
        float a, d;
        filt8(f0.x, f0.y, f1.x, f1.y, f2.x, f2.y, f3.x, f3.y, a, d);
        gcd[i] = d;
        if (r & 1)
            *reinterpret_cast<float2*>(drow + (i - 1 - lo + 6)) = make_float2(aprev, a);
        else
            aprev = a;
        if (MG) {
            if (lo == 0 && i < 6) drow[5 - i] = a;
            if (hi == DL && i >= DL - 7) drow[(2 * DL - 1 - i) - lo + 6] = a;
        }
        f0 = f1; f1 = f2; f2 = f3;
    }
    if (MG && (span & 1) && slot == 15) {
        const int i = hi - 1;
        const float* s = srow - slo + 6;  // s[t] = sample t
        float a, d;
        filt8(s[2*i-6], s[2*i-5], s[2*i-4], s[2*i-3], s[2*i-2], s[2*i-1], s[2*i], s[2*i+1], a, d);
        gcd[i] = d;
        drow[i - lo + 6] = a;
        if (hi == DL && i >= DL - 7) drow[(2 * DL - 1 - i) - lo + 6] = a;
    }
}

// Level 4: scalar LDS window (no parity constraint), direct cA4/cD4 stores.
__device__ __forceinline__ void level4(
    const float* __restrict__ srow, int slo,
    float* __restrict__ gca, float* __restrict__ gcd,
    int lo, int hi, int slot) {
    const int span = hi - lo;
    const int i0 = lo + min(slot * 3, span - 3);
    const float* s = srow - slo + 6;  // s[t] = sample t
    float w[8];
#pragma unroll
    for (int k = 0; k < 8; ++k) w[k] = s[2 * i0 - 6 + k];
#pragma unroll
    for (int r = 0; r < 3; ++r) {
        const int i = i0 + r;
        if (r) {
#pragma unroll
            for (int k = 0; k < 6; ++k) w[k] = w[k + 2];
            w[6] = s[2 * i];
            w[7] = s[2 * i + 1];
        }
        float a, d;
        filt8(w[0], w[1], w[2], w[3], w[4], w[5], w[6], w[7], a, d);
        gca[i] = a;
        gcd[i] = d;
    }
}

template <bool MG>
__device__ __forceinline__ void cascade(
    const float* xc, float* b1, float* b2, float* b3,
    float* gcd1, float* gcd2, float* gcd3, float* gcd4, float* gca4,
    int c, int slot,
    int lo1, int hi1, int lo2, int hi2, int lo3, int hi3, int lo4, int hi4) {
    level1<MG>(xc, b1 + c * LP1, gcd1, lo1, hi1, slot);
    __syncthreads();
    levelmid<10, MG>(b1 + c * LP1, lo1, b2 + c * LP2, L2C, gcd2, lo2, hi2, slot);
    __syncthreads();
    levelmid<6, MG>(b2 + c * LP2, lo2, b3 + c * LP3, L3C, gcd3, lo3, hi3, slot);
    __syncthreads();
    level4(b3 + c * LP3, lo3, gca4, gcd4, lo4, hi4, slot);
}

__global__ __launch_bounds__(NT, 4) void fused_dwt_kernel(
    const float* __restrict__ x, float* __restrict__ out) {
    __shared__ __align__(16) float b1[32 * LP1];
    __shared__ __align__(16) float b2[32 * LP2];
    __shared__ __align__(16) float b3[32 * LP3];

    const int bid = blockIdx.x;
    const int tile = bid & 7;   // cA4 tile 0..7
    const int b = bid >> 3;     // batch 0..63

    const int tid = threadIdx.x;
    const int c = tid & 31;     // channel (lane 0-31 => coalesced x lines)
    const int slot = tid >> 5;  // 0..15

    const int lo4 = 33 * tile, hi4 = min(L4C, lo4 + 33);
    const int lo3 = max(0, 2 * lo4 - 6), hi3 = min(L3C, 2 * hi4);
    const int lo2 = max(0, 2 * lo3 - 6), hi2 = min(L2C, 2 * hi3);
    const int lo1 = max(0, 2 * lo2 - 6), hi1 = min(L1C, 2 * hi2);

    const int sig = b * 32 + c;
    const float* xc = x + (size_t)b * (L0C * 32) + c;
    float* gca4 = out + (size_t)sig * L4C;
    float* gcd4 = out + OFF_CD4 + (size_t)sig * L4C;
    float* gcd3 = out + OFF_CD3 + (size_t)sig * L3C;
    float* gcd2 = out + OFF_CD2 + (size_t)sig * L2C;
    float* gcd1 = out + OFF_CD1 + (size_t)sig * L1C;

    if (tile == 0 || tile == 7)
        cascade<true>(xc, b1, b2, b3, gcd1, gcd2, gcd3, gcd4, gca4, c, slot,
                      lo1, hi1, lo2, hi2, lo3, hi3, lo4, hi4);
    else
        cascade<false>(xc, b1, b2, b3, gcd1, gcd2, gcd3, gcd4, gca4, c, slot,
                       lo1, hi1, lo2, hi2, lo3, hi3, lo4, hi4);
}

extern "C" void kernel_launch(void* const* d_in, const int* in_sizes, int n_in,
                              void* d_out, int out_size, void* d_ws, size_t ws_size,
                              hipStream_t stream) {
    (void)in_sizes; (void)n_in; (void)d_ws; (void)ws_size; (void)out_size;
    const float* x = (const float*)d_in[0];
    float* out = (float*)d_out;
    fused_dwt_kernel<<<dim3(512), dim3(NT), 0, stream>>>(x, out);
}

// Round 8
// 32.896 us; speedup vs baseline: 1.5103x; 1.5103x over previous
//
#include <hip/hip_runtime.h>

// Fully-fused 4-level db4 wavedec ('symmetric'), faithful to the JAX/pywt reference.
// x: [B=64, L=4096, C=32] f32. Out flat: cA4,cD4,cD3,cD2,cD1 each [B,C,len].
// lens: 4096 -> 2051 -> 1029 -> 518 -> 262.
// Block = (batch, 2-ch group, tile of 33 cA4 outputs); 8192 blocks x 256 thr.
// KEY CHANGE vs r6: ALL global stores deferred to after the final barrier
// (separate LDS staging for cd1..cd4,ca4). Every inter-level barrier now only
// drains LDS (lgkmcnt), not HBM stores (vmcnt) -- removing the per-barrier
// store-drain stall that pinned rounds 2-6 at ~31 us.

#define NT 256
#define NCHB 2

// Window-row pitches (floats), == 2 mod 4: b64 window starts spread uniformly.
#define LPX 634  // x span <= 618 (+13 margins)
#define LP1 322  // l1 span <= 306
#define LP2 166  // l2 span <= 150
#define LP3 86   // l3 span <= 72
// Output staging pitches.
#define CDP1 314 // cd1 span <= 306
#define CDP2 154 // cd2 span <= 150
#define CDP3 82  // cd3 span <= 78
#define CDP4 40  // cd4 span <= 33
#define CAP4 40  // ca4 span <= 33

#define L0C 4096
#define L1C 2051
#define L2C 1029
#define L3C 518
#define L4C 262
#define SC 2048

#define OFF_CD4 ((size_t)SC * L4C)
#define OFF_CD3 ((size_t)2 * SC * L4C)
#define OFF_CD2 (OFF_CD3 + (size_t)SC * L3C)
#define OFF_CD1 (OFF_CD2 + (size_t)SC * L2C)

__device__ __forceinline__ void filt8(
    const float w0, const float w1, const float w2, const float w3,
    const float w4, const float w5, const float w6, const float w7,
    float& a, float& d) {
    // db4 correlation kernels (dec_lo reversed = _H; dec_hi reversed), split trees.
    constexpr float FLO[8] = {
        0.23037781330885523f,  0.7148465705525415f,  0.6308807679295904f,
        -0.02798376941698385f, -0.18703481171888114f, 0.030841381835986965f,
        0.032883011666982945f, -0.010597401784997278f};
    constexpr float FHI[8] = {
        -0.010597401784997278f, -0.032883011666982945f, 0.030841381835986965f,
        0.18703481171888114f,  -0.02798376941698385f,  -0.6308807679295904f,
        0.7148465705525415f,   -0.23037781330885523f};
    float a0 = FLO[0] * w0;
    a0 = fmaf(FLO[1], w1, a0); a0 = fmaf(FLO[2], w2, a0); a0 = fmaf(FLO[3], w3, a0);
    float a1 = FLO[4] * w4;
    a1 = fmaf(FLO[5], w5, a1); a1 = fmaf(FLO[6], w6, a1); a1 = fmaf(FLO[7], w7, a1);
    a = a0 + a1;
    float d0 = FHI[0] * w0;
    d0 = fmaf(FHI[1], w1, d0); d0 = fmaf(FHI[2], w2, d0); d0 = fmaf(FHI[3], w3, d0);
    float d1 = FHI[4] * w4;
    d1 = fmaf(FHI[5], w5, d1); d1 = fmaf(FHI[6], w6, d1); d1 = fmaf(FHI[7], w7, d1);
    d = d0 + d1;
}

template <int R, bool LAST>
__device__ __forceinline__ void level_run(
    const float* __restrict__ src, int PS, int srclo,
    float* __restrict__ dst, int PD, int DL,
    int lo, int hi,
    float* __restrict__ cdbuf, int CDP,
    float* __restrict__ cabuf,
    int c, int slot) {
    const int span = hi - lo;
    int i0r = slot * R;
    if (i0r > span - R) i0r = span - R;  // clamp (duplicates idempotent)
    const int i0 = lo + i0r;

    const float2* row2 = reinterpret_cast<const float2*>(src + c * PS);
    int p = i0 - (srclo >> 1);  // sample t at word t-srclo+6; first tap t=2i-6
    float2 f0 = row2[p], f1 = row2[p + 1], f2 = row2[p + 2];
    float* drow = LAST ? nullptr : dst + c * PD;
    float* cdrow = cdbuf + c * CDP - lo;
    float* carow = LAST ? cabuf + c * CAP4 - lo : nullptr;

#pragma unroll
    for (int r = 0; r < R; ++r) {
        const float2 f3 = row2[p + 3 + r];
        const int i = i0 + r;
        float a, d;
        filt8(f0.x, f0.y, f1.x, f1.y, f2.x, f2.y, f3.x, f3.y, a, d);

        if constexpr (!LAST) {
            drow[i - lo + 6] = a;
            // reflection margins for next level (boundary tiles only)
            if (lo == 0 && i < 6) drow[5 - i] = a;
            if (hi == DL && i >= DL - 7) drow[(2 * DL - 1 - i) - lo + 6] = a;
        } else {
            carow[i] = a;
        }
        cdrow[i] = d;
        f0 = f1; f1 = f2; f2 = f3;
    }
}

__device__ __forceinline__ void dump_rows(
    const float* __restrict__ buf, int pitch, int bufLo,
    float* __restrict__ gbase, int rowLen, int ownLo, int ownHi, int tid) {
    const int span = ownHi - ownLo;
#pragma unroll
    for (int c2 = 0; c2 < NCHB; ++c2) {
        float* g = gbase + (size_t)c2 * rowLen + ownLo;
        const float* s = buf + c2 * pitch + (ownLo - bufLo);
        for (int i = tid; i < span; i += NT) g[i] = s[i];
    }
}

__global__ __launch_bounds__(NT, 8) void fused_dwt_kernel(
    const float* __restrict__ x, float* __restrict__ out) {
    __shared__ __align__(16) float bx[NCHB * LPX];
    __shared__ __align__(16) float b1[NCHB * LP1];
    __shared__ __align__(16) float b2[NCHB * LP2];
    __shared__ __align__(16) float b3[NCHB * LP3];
    __shared__ __align__(16) float cd1[NCHB * CDP1];
    __shared__ __align__(16) float cd2[NCHB * CDP2];
    __shared__ __align__(16) float cd3[NCHB * CDP3];
    __shared__ __align__(16) float cd4[NCHB * CDP4];
    __shared__ __align__(16) float ca4[NCHB * CAP4];

    // XCD swizzle: 8192 blocks = 8 XCDs x 1024 contiguous works; the 16
    // channel-group siblings (consecutive works) share one XCD's L2.
    const int bid = blockIdx.x;
    const int work = (bid & 7) * 1024 + (bid >> 3);
    const int cg = work & 15;          // channel group 0..15 (2 ch each)
    const int tile = (work >> 4) & 7;  // cA4 tile 0..7
    const int b = work >> 7;           // batch 0..63

    const int tid = threadIdx.x;
    const int c = tid & 1;
    const int slot = tid >> 1;  // 0..127
    const int c0 = cg * 2;
    const int sigB = b * 32 + c0;

    const int lo4 = 33 * tile, hi4 = min(L4C, lo4 + 33);
    const int lo3 = max(0, 2 * lo4 - 6), hi3 = min(L3C, 2 * hi4);
    const int lo2 = max(0, 2 * lo3 - 6), hi2 = min(L2C, 2 * hi3);
    const int lo1 = max(0, 2 * lo2 - 6), hi1 = min(L1C, 2 * hi2);
    const int lox = max(0, 2 * lo1 - 6), hix = min(L0C, 2 * hi1);

    // ---- stage x tile into transposed rows, float2 pair writes (+ reflections) ----
    const float* xb = x + (size_t)b * (L0C * 32) + c0;
    const int npair = (hix - lox) >> 1;
    for (int q = tid; q < npair; q += NT) {
        const int j = q << 1;
        const int t = lox + j;
        const float2 va = *reinterpret_cast<const float2*>(xb + (size_t)t * 32);
        const float2 vb = *reinterpret_cast<const float2*>(xb + (size_t)(t + 1) * 32);
        const float avv[2] = {va.x, va.y};
        const float bvv[2] = {vb.x, vb.y};
#pragma unroll
        for (int hh = 0; hh < NCHB; ++hh)
            *reinterpret_cast<float2*>(bx + hh * LPX + 6 + j) = make_float2(avv[hh], bvv[hh]);
        if (lox == 0 && t < 6) {
#pragma unroll
            for (int hh = 0; hh < NCHB; ++hh) {
                bx[hh * LPX + 5 - t] = avv[hh];
                if (t + 1 < 6) bx[hh * LPX + 4 - t] = bvv[hh];
            }
        }
        if (hix == L0C && t + 1 >= L0C - 7) {
#pragma unroll
            for (int hh = 0; hh < NCHB; ++hh) {
                if (t >= L0C - 7) bx[hh * LPX + (2 * L0C - 1 - t) - lox + 6] = avv[hh];
                bx[hh * LPX + (2 * L0C - 2 - t) - lox + 6] = bvv[hh];
            }
        }
    }
    __syncthreads();

    // d_out chunk bases for this block's channels
    float* gca4 = out + (size_t)sigB * L4C;
    float* gcd4 = out + OFF_CD4 + (size_t)sigB * L4C;
    float* gcd3 = out + OFF_CD3 + (size_t)sigB * L3C;
    float* gcd2 = out + OFF_CD2 + (size_t)sigB * L2C;
    float* gcd1 = out + OFF_CD1 + (size_t)sigB * L1C;

    // owned (exclusive, tile-partitioned) detail ranges
    const int o1lo = tile ? 264 * tile - 34 : 0;
    const int o1hi = (tile == 7) ? L1C : 264 * tile + 230;
    const int o2lo = tile ? 132 * tile - 10 : 0;
    const int o2hi = (tile == 7) ? L2C : 132 * tile + 122;
    const int o3lo = tile ? 66 * tile - 2 : 0;
    const int o3hi = (tile == 7) ? L3C : 66 * tile + 64;

    // ---- all 4 levels: LDS-only traffic between barriers ----
    level_run<3, false>(bx, LPX, lox, b1, LP1, L1C, lo1, hi1, cd1, CDP1, nullptr, c, slot);
    __syncthreads();
    level_run<2, false>(b1, LP1, lo1, b2, LP2, L2C, lo2, hi2, cd2, CDP2, nullptr, c, slot);
    __syncthreads();
    level_run<1, false>(b2, LP2, lo2, b3, LP3, L3C, lo3, hi3, cd3, CDP3, nullptr, c, slot);
    __syncthreads();
    level_run<1, true>(b3, LP3, lo3, nullptr, 0, L4C, lo4, hi4, cd4, CDP4, ca4, c, slot);
    __syncthreads();

    // ---- single terminal dump: no barrier after any global store ----
    dump_rows(cd1, CDP1, lo1, gcd1, L1C, o1lo, o1hi, tid);
    dump_rows(cd2, CDP2, lo2, gcd2, L2C, o2lo, o2hi, tid);
    dump_rows(cd3, CDP3, lo3, gcd3, L3C, o3lo, o3hi, tid);
    dump_rows(cd4, CDP4, lo4, gcd4, L4C, lo4, hi4, tid);
    dump_rows(ca4, CAP4, lo4, gca4, L4C, lo4, hi4, tid);
}

extern "C" void kernel_launch(void* const* d_in, const int* in_sizes, int n_in,
                              void* d_out, int out_size, void* d_ws, size_t ws_size,
                              hipStream_t stream) {
    (void)in_sizes; (void)n_in; (void)d_ws; (void)ws_size; (void)out_size;
    const float* x = (const float*)d_in[0];
    float* out = (float*)d_out;
    fused_dwt_kernel<<<dim3(8192), dim3(NT), 0, stream>>>(x, out);
}

// Round 9
// 30.107 us; speedup vs baseline: 1.6502x; 1.0927x over previous
//
#include <hip/hip_runtime.h>

// Fully-fused 4-level db4 wavedec ('symmetric'), faithful to the JAX/pywt reference.
// x: [B=64, L=4096, C=32] f32. Out flat: cA4,cD4,cD3,cD2,cD1 each [B,C,len].
// lens: 4096 -> 2051 -> 1029 -> 518 -> 262.
// Block = (batch, 4-ch group, tile of 33 cA4 outputs); 4096 blocks x 256 thr.
// vs r8: exact slot<->span matching (no duplicate tail recompute; surplus slots
// idle), paired float2 LDS writes + float2 dumps, int-only addressing, NCHB=4
// (half the threads). ~2x dynamic-instruction reduction on VALU and DS pipes.

#define NT 256
#define NCHB 4

// Window-row pitches (floats), == 2 mod 4 (pitch/2 odd): b64 accesses spread
// 4 lanes/bank-pair (the wave64 b64 minimum) for run strides R=6/4/2.
#define LPX 634  // x span <= 618 (+6 left, +7 right margins)
#define LP1 322  // l1 span <= 306
#define LP2 166  // l2 span <= 150
#define LP3 86   // l3 span <= 72
// Output staging pitches (even).
#define CDP1 314 // cd1 span <= 306
#define CDP2 154 // cd2 span <= 150
#define CDP3 82  // cd3 span <= 72
#define CDP4 40  // cd4 span <= 33
#define CAP4 40  // ca4 span <= 33

#define L0C 4096
#define L1C 2051
#define L2C 1029
#define L3C 518
#define L4C 262
#define SC 2048

// All output offsets fit in int (out_size ~ 8.44M floats).
#define OFF_CD4 (SC * L4C)
#define OFF_CD3 (2 * SC * L4C)
#define OFF_CD2 (OFF_CD3 + SC * L3C)
#define OFF_CD1 (OFF_CD2 + SC * L2C)

__device__ __forceinline__ void filt8(
    const float w0, const float w1, const float w2, const float w3,
    const float w4, const float w5, const float w6, const float w7,
    float& a, float& d) {
    // db4 correlation kernels (dec_lo reversed = _H; dec_hi reversed), split trees.
    constexpr float FLO[8] = {
        0.23037781330885523f,  0.7148465705525415f,  0.6308807679295904f,
        -0.02798376941698385f, -0.18703481171888114f, 0.030841381835986965f,
        0.032883011666982945f, -0.010597401784997278f};
    constexpr float FHI[8] = {
        -0.010597401784997278f, -0.032883011666982945f, 0.030841381835986965f,
        0.18703481171888114f,  -0.02798376941698385f,  -0.6308807679295904f,
        0.7148465705525415f,   -0.23037781330885523f};
    float a0 = FLO[0] * w0;
    a0 = fmaf(FLO[1], w1, a0); a0 = fmaf(FLO[2], w2, a0); a0 = fmaf(FLO[3], w3, a0);
    float a1 = FLO[4] * w4;
    a1 = fmaf(FLO[5], w5, a1); a1 = fmaf(FLO[6], w6, a1); a1 = fmaf(FLO[7], w7, a1);
    a = a0 + a1;
    float d0 = FHI[0] * w0;
    d0 = fmaf(FHI[1], w1, d0); d0 = fmaf(FHI[2], w2, d0); d0 = fmaf(FHI[3], w3, d0);
    float d1 = FHI[4] * w4;
    d1 = fmaf(FHI[5], w5, d1); d1 = fmaf(FHI[6], w6, d1); d1 = fmaf(FHI[7], w7, d1);
    d = d0 + d1;
}

// One even-aligned run of R outputs (R even). Full runs tile the span exactly;
// the one remainder slot does an even-clamped run (+ scalar tail if span odd);
// all higher slots return immediately (no duplicate work).
template <int R, bool MG, bool LAST>
__device__ __forceinline__ void level_run(
    const float* __restrict__ src, int PS, int srclo,
    float* __restrict__ dst, int PD, int DL,
    int lo, int hi,
    float* __restrict__ cdbuf, int CDP,
    float* __restrict__ cabuf,
    int c, int slot) {
    static_assert((R & 1) == 0, "R must be even");
    const int span = hi - lo;
    const int nrun = span / R;
    bool tail = false;
    int i0;
    if (slot < nrun) {
        i0 = lo + slot * R;
    } else if (slot == nrun && nrun * R < span) {
        i0 = lo + ((span - R) & ~1);
        tail = (span & 1) != 0;
    } else {
        return;
    }

    const float* rowb = src + c * PS;
    const float2* row2 = reinterpret_cast<const float2*>(rowb);
    const int p = i0 - (srclo >> 1);  // sample t at word t-srclo+6; first tap t=2*i0-6
    float2 f0 = row2[p], f1 = row2[p + 1], f2 = row2[p + 2];

    float* dbase = LAST ? nullptr : dst + c * PD;
    float* cdbase = cdbuf + c * CDP;
    float* cabase = LAST ? cabuf + c * CAP4 : nullptr;

    float ap = 0.f, dp = 0.f;
#pragma unroll
    for (int r = 0; r < R; ++r) {
        const float2 f3 = row2[p + 3 + r];
        const int i = i0 + r;
        float a, d;
        filt8(f0.x, f0.y, f1.x, f1.y, f2.x, f2.y, f3.x, f3.y, a, d);
        if (r & 1) {
            const int w = i - 1 - lo;  // even
            if constexpr (!LAST)
                *reinterpret_cast<float2*>(dbase + w + 6) = make_float2(ap, a);
            else
                *reinterpret_cast<float2*>(cabase + w) = make_float2(ap, a);
            *reinterpret_cast<float2*>(cdbase + w) = make_float2(dp, d);
        } else {
            ap = a; dp = d;
        }
        if constexpr (MG && !LAST) {
            // reflection margins for the next level (boundary tiles only)
            if (lo == 0 && i < 6) dbase[5 - i] = a;
            if (hi == DL && i >= DL - 7) dbase[(2 * DL - 1 - i) - lo + 6] = a;
        }
        f0 = f1; f1 = f2; f2 = f3;
    }
    if (tail) {
        const int i = hi - 1;
        const float* s = rowb + 6 - srclo;  // s[t] = sample t
        float a, d;
        filt8(s[2*i-6], s[2*i-5], s[2*i-4], s[2*i-3],
              s[2*i-2], s[2*i-1], s[2*i],   s[2*i+1], a, d);
        if constexpr (!LAST) {
            dbase[i - lo + 6] = a;
            if constexpr (MG) {
                if (hi == DL && i >= DL - 7) dbase[(2 * DL - 1 - i) - lo + 6] = a;
            }
        } else {
            cabase[i - lo] = a;
        }
        cdbase[i - lo] = d;
    }
}

// Dump staged rows to global: float2 LDS reads, two dword stores sharing one
// address (coalesced across lanes). (ownLo - bufLo) is even for all levels.
__device__ __forceinline__ void dump_rows(
    const float* __restrict__ buf, int pitch, int bufLo,
    float* __restrict__ gbase, int rowLen, int ownLo, int ownHi, int tid) {
    const int span = ownHi - ownLo;
    const int n2 = span >> 1;
    const int off = ownLo - bufLo;
#pragma unroll
    for (int c2 = 0; c2 < NCHB; ++c2) {
        const float2* s2 = reinterpret_cast<const float2*>(buf + c2 * pitch + off);
        float* g = gbase + c2 * rowLen + ownLo;
        for (int k = tid; k < n2; k += NT) {
            const float2 v = s2[k];
            g[2 * k] = v.x;
            g[2 * k + 1] = v.y;
        }
        if ((span & 1) && tid == 0) g[span - 1] = buf[c2 * pitch + off + span - 1];
    }
}

template <bool MG>
__device__ __forceinline__ void cascade(
    const float* bx, float* b1, float* b2, float* b3,
    float* cd1, float* cd2, float* cd3, float* cd4, float* ca4,
    float* __restrict__ out, int sigB, int tile, int c, int slot, int tid,
    int lox, int lo1, int hi1, int lo2, int hi2, int lo3, int hi3,
    int lo4, int hi4) {
    // owned (exclusive, tile-partitioned) detail ranges
    const int o1lo = tile ? 264 * tile - 34 : 0;
    const int o1hi = (tile == 7) ? L1C : 264 * tile + 230;
    const int o2lo = tile ? 132 * tile - 10 : 0;
    const int o2hi = (tile == 7) ? L2C : 132 * tile + 122;
    const int o3lo = tile ? 66 * tile - 2 : 0;
    const int o3hi = (tile == 7) ? L3C : 66 * tile + 64;

    level_run<6, MG, false>(bx, LPX, lox, b1, LP1, L1C, lo1, hi1, cd1, CDP1,
                            nullptr, c, slot);
    __syncthreads();

    dump_rows(cd1, CDP1, lo1, out + OFF_CD1 + sigB * L1C, L1C, o1lo, o1hi, tid);
    level_run<4, MG, false>(b1, LP1, lo1, b2, LP2, L2C, lo2, hi2, cd2, CDP2,
                            nullptr, c, slot);
    __syncthreads();

    dump_rows(cd2, CDP2, lo2, out + OFF_CD2 + sigB * L2C, L2C, o2lo, o2hi, tid);
    level_run<2, MG, false>(b2, LP2, lo2, b3, LP3, L3C, lo3, hi3, cd3, CDP3,
                            nullptr, c, slot);
    __syncthreads();

    dump_rows(cd3, CDP3, lo3, out + OFF_CD3 + sigB * L3C, L3C, o3lo, o3hi, tid);
    level_run<2, MG, true>(b3, LP3, lo3, nullptr, 0, L4C, lo4, hi4, cd4, CDP4,
                           ca4, c, slot);
    __syncthreads();

    dump_rows(cd4, CDP4, lo4, out + OFF_CD4 + sigB * L4C, L4C, lo4, hi4, tid);
    dump_rows(ca4, CAP4, lo4, out + sigB * L4C, L4C, lo4, hi4, tid);
}

__global__ __launch_bounds__(NT, 5) void fused_dwt_kernel(
    const float* __restrict__ x, float* __restrict__ out) {
    __shared__ __align__(16) float bx[NCHB * LPX];
    __shared__ __align__(16) float b1[NCHB * LP1];
    __shared__ __align__(16) float b2[NCHB * LP2];
    __shared__ __align__(16) float b3[NCHB * LP3];
    __shared__ __align__(16) float cd1[NCHB * CDP1];
    __shared__ __align__(16) float cd2[NCHB * CDP2];
    __shared__ __align__(16) float cd3[NCHB * CDP3];
    __shared__ __align__(16) float cd4[NCHB * CDP4];
    __shared__ __align__(16) float ca4[NCHB * CAP4];

    // XCD swizzle: 4096 blocks = 8 XCDs x 512 contiguous works; the 8
    // channel-group siblings (consecutive works) share one XCD's L2.
    const int bid = blockIdx.x;
    const int work = (bid & 7) * 512 + (bid >> 3);
    const int cg = work & 7;           // channel group 0..7 (4 ch each)
    const int tile = (work >> 3) & 7;  // cA4 tile 0..7
    const int b = work >> 6;           // batch 0..63

    const int tid = threadIdx.x;
    const int c = tid & 3;
    const int slot = tid >> 2;  // 0..63
    const int c0 = cg * 4;
    const int sigB = b * 32 + c0;

    const int lo4 = 33 * tile, hi4 = min(L4C, lo4 + 33);
    const int lo3 = max(0, 2 * lo4 - 6), hi3 = min(L3C, 2 * hi4);
    const int lo2 = max(0, 2 * lo3 - 6), hi2 = min(L2C, 2 * hi3);
    const int lo1 = max(0, 2 * lo2 - 6), hi1 = min(L1C, 2 * hi2);
    const int lox = max(0, 2 * lo1 - 6), hix = min(L0C, 2 * hi1);

    // ---- stage x tile into transposed rows: one float4 covers the block's 4
    // channels; float2 pair writes per row (+ reflection margins) ----
    const float* xb = x + b * (L0C * 32) + c0;
    const int npair = (hix - lox) >> 1;
    for (int q = tid; q < npair; q += NT) {
        const int j = q << 1;
        const int t = lox + j;
        const float4 va = *reinterpret_cast<const float4*>(xb + t * 32);
        const float4 vb = *reinterpret_cast<const float4*>(xb + t * 32 + 32);
        const float av[4] = {va.x, va.y, va.z, va.w};
        const float bv[4] = {vb.x, vb.y, vb.z, vb.w};
#pragma unroll
        for (int hh = 0; hh < NCHB; ++hh)
            *reinterpret_cast<float2*>(bx + hh * LPX + 6 + j) =
                make_float2(av[hh], bv[hh]);
        if (lox == 0 && t < 6) {
#pragma unroll
            for (int hh = 0; hh < NCHB; ++hh) {
                bx[hh * LPX + 5 - t] = av[hh];
                if (t + 1 < 6) bx[hh * LPX + 4 - t] = bv[hh];
            }
        }
        if (hix == L0C && t + 1 >= L0C - 7) {
#pragma unroll
            for (int hh = 0; hh < NCHB; ++hh) {
                if (t >= L0C - 7) bx[hh * LPX + (2 * L0C - 1 - t) - lox + 6] = av[hh];
                bx[hh * LPX + (2 * L0C - 2 - t) - lox + 6] = bv[hh];
            }
        }
    }
    __syncthreads();

    if (tile == 0 || tile == 7)
        cascade<true>(bx, b1, b2, b3, cd1, cd2, cd3, cd4, ca4, out, sigB, tile,
                      c, slot, tid, lox, lo1, hi1, lo2, hi2, lo3, hi3, lo4, hi4);
    else
        cascade<false>(bx, b1, b2, b3, cd1, cd2, cd3, cd4, ca4, out, sigB, tile,
                       c, slot, tid, lox, lo1, hi1, lo2, hi2, lo3, hi3, lo4, hi4);
}

extern "C" void kernel_launch(void* const* d_in, const int* in_sizes, int n_in,
                              void* d_out, int out_size, void* d_ws, size_t ws_size,
                              hipStream_t stream) {
    (void)in_sizes; (void)n_in; (void)d_ws; (void)ws_size; (void)out_size;
    const float* x = (const float*)d_in[0];
    float* out = (float*)d_out;
    fused_dwt_kernel<<<dim3(4096), dim3(NT), 0, stream>>>(x, out);
}